// Round 8
// baseline (329.646 us; speedup 1.0000x reference)
//
#include <hip/hip_runtime.h>
#include <hip/hip_bf16.h>

typedef __hip_bfloat16 bf16;
typedef __attribute__((ext_vector_type(8))) short short8;
typedef __attribute__((ext_vector_type(4))) float float4v;

#define Hd 256
#define Wd 256
#define HW 65536
#define CO 64

// ---------------------------------------------------------------------------
// K1: style MLP + modulated/demodulated weights. One block per (o, s).
// wA layout: [s][kc(18)][o(64)][32], k = tap*64 + i (tap-major).
// ---------------------------------------------------------------------------
__global__ __launch_bounds__(64) void k1_style(
    const float* __restrict__ vec, const float* __restrict__ w1,
    const float* __restrict__ w2, const float* __restrict__ wconv,
    bf16* __restrict__ wA)
{
    int o = blockIdx.x;      // 0..63
    int s = blockIdx.y;      // 0..7
    int i = threadIdx.x;     // lane = input channel

    float sv[4];
#pragma unroll
    for (int q = 0; q < 4; ++q) sv[q] = vec[s * 256 + q * 64 + i];

    float hid[16];
#pragma unroll
    for (int j = 0; j < 16; ++j) {
        float p = 0.f;
#pragma unroll
        for (int q = 0; q < 4; ++q) p += sv[q] * w1[j * 256 + q * 64 + i];
#pragma unroll
        for (int off = 32; off >= 1; off >>= 1) p += __shfl_xor(p, off, 64);
        hid[j] = p > 0.f ? p : 0.1f * p;   // LeakyReLU(0.1)
    }
    float sty = 0.f;
#pragma unroll
    for (int j = 0; j < 16; ++j) sty += w2[i * 16 + j] * hid[j];
    float msty = sty + 1.0f;               // per input-channel i

    float wrow[9];
#pragma unroll
    for (int tt = 0; tt < 9; ++tt) wrow[tt] = wconv[(o * 64 + i) * 9 + tt] * msty;
    float ss = 0.f;
#pragma unroll
    for (int tt = 0; tt < 9; ++tt) ss += wrow[tt] * wrow[tt];
#pragma unroll
    for (int off = 32; off >= 1; off >>= 1) ss += __shfl_xor(ss, off, 64);
    float d = rsqrtf(ss + 1e-8f);

    bf16* wAs = wA + s * (18 * 64 * 32);
#pragma unroll
    for (int tt = 0; tt < 9; ++tt) {
        int k = tt * 64 + i;
        wAs[(k >> 5) * 2048 + o * 32 + (k & 31)] = (bf16)(wrow[tt] * d);
    }
}

// ---------------------------------------------------------------------------
// K2 v2: ChanNorm + transpose, PERFECTLY COALESCED both directions.
// (v1 read 64 B segments -> ~2x HBM over-fetch on x; est. 65-70 us.)
// Block = 128 px of one row (grid 512 x 8); wave = 32-px window x all 64 ch.
// Lane micro-tile: po=lane&7 (px octet: 8 lanes x float4 = 128 B line),
// cg=lane>>3 (channel octet). Loads: 8 insts, each 8 full 128 B lines.
// Stats: reduce over cg via __shfl_xor(8/16/32). Stores: normalize+pack
// bf16 into a wave-private 4 KB LDS block (identity byte mapping to the
// nx block), then flush linearly: 4 x 1 KB fully-coalesced stores.
// Both LDS phases verified bank-even (8 lanes/bank-group = the floor).
// ---------------------------------------------------------------------------
__global__ __launch_bounds__(256) void k2_norm(
    const float* __restrict__ x, const float* __restrict__ gg,
    const float* __restrict__ bb, bf16* __restrict__ nx,
    float2* __restrict__ sms)
{
    int bx  = blockIdx.x;            // 0..511
    int h   = bx >> 1;
    int seg = (bx & 1) * 128;
    int s   = blockIdx.y;
    int t   = threadIdx.x;
    int wave = t >> 6, lane = t & 63;
    int po = lane & 7;               // px: pxw + po*4 .. +3
    int cg = lane >> 3;              // channels cg*8 .. +7

    __shared__ __align__(16) char lbuf[4][4096];

    int pxw = seg + wave * 32;       // this wave's 32-px window
    const float* xrow = x + (size_t)s * ((size_t)CO * HW) + (size_t)h * Wd;

    float4 v[8];
#pragma unroll
    for (int c = 0; c < 8; ++c)
        v[c] = *(const float4*)&xrow[(size_t)(cg * 8 + c) * HW + pxw + po * 4];

    float s1[4], s2[4];
#pragma unroll
    for (int pi = 0; pi < 4; ++pi) {
        float a = 0.f, q = 0.f;
#pragma unroll
        for (int c = 0; c < 8; ++c) { float f = (&v[c].x)[pi]; a += f; q += f * f; }
        s1[pi] = a; s2[pi] = q;
    }
#pragma unroll
    for (int off = 8; off <= 32; off <<= 1)
#pragma unroll
        for (int pi = 0; pi < 4; ++pi) {
            s1[pi] += __shfl_xor(s1[pi], off, 64);
            s2[pi] += __shfl_xor(s2[pi], off, 64);
        }
    float mean[4], rstd[4];
#pragma unroll
    for (int pi = 0; pi < 4; ++pi) {
        mean[pi] = s1[pi] * (1.f / 64);
        float var = s2[pi] * (1.f / 64) - mean[pi] * mean[pi] + 1e-5f;
        rstd[pi] = rsqrtf(var);
    }
    if (cg == 0) {
        float2* smsrow = sms + (size_t)s * HW + (size_t)h * Wd;
#pragma unroll
        for (int pi = 0; pi < 4; ++pi) {
            float var = s2[pi] * (1.f / 64) - mean[pi] * mean[pi] + 1e-5f;
            smsrow[pxw + po * 4 + pi] = make_float2(mean[pi], var * rstd[pi]); // std
        }
    }

    float4 gA = *(const float4*)&gg[cg * 8], gB = *(const float4*)&gg[cg * 8 + 4];
    float4 bA = *(const float4*)&bb[cg * 8], bB = *(const float4*)&bb[cg * 8 + 4];
#pragma unroll
    for (int pi = 0; pi < 4; ++pi) {
        union { uint4 u; bf16 hh[8]; } ov;
#pragma unroll
        for (int c = 0; c < 8; ++c) {
            float gv = (c < 4) ? (&gA.x)[c] : (&gB.x)[c - 4];
            float bv = (c < 4) ? (&bA.x)[c] : (&bB.x)[c - 4];
            ov.hh[c] = (bf16)(((&v[c].x)[pi] - mean[pi]) * rstd[pi] * gv + bv);
        }
        int p = po * 4 + pi;        // px-local 0..31
        *(uint4*)&lbuf[wave][(size_t)p * 128 + cg * 16] = ov.u;
    }
    __syncthreads();
    // flush: LDS byte j == nx-block byte j (identity mapping)
    bf16* nxw = nx + ((size_t)s * HW + (size_t)h * Wd + pxw) * CO;
#pragma unroll
    for (int i = 0; i < 4; ++i) {
        uint4 d = *(uint4*)&lbuf[wave][i * 1024 + lane * 16];
        *(uint4*)((char*)nxw + i * 1024 + lane * 16) = d;
    }
}

// ---------------------------------------------------------------------------
// K3: implicit-GEMM 3x3 conv + residual, consuming channel-last nx.
// Block = (s, 8 output rows, 32-px strip). Halo tile 10 rows x 34 px.
// P1 stage = pure vectorized copy (16 x uint4/thread), ONE barrier.
// Compute: kc-outer (unroll 1), A-pair double-buffered one kc ahead from
// L2-hot wA (no big resident arrays -> no spill; VGPR ~120).
// Epilogue v2: nx re-read as ds_read_b64 (4 consecutive o per read; was
// 64 scattered ds_read_u16 -> 4x fewer LDS insts, fewer conflicts);
// sbi hoisted to registers before the row loop.
// Residual: x = (nx - b[o]) / g[o] * std + mean  (no HBM re-read).
// ---------------------------------------------------------------------------
#define PXB 32
#define ROWS 8
#define TR 10
#define WL 34
#define NSITES (TR * WL)          // 340
#define ROW_ELEMS (8 * WL * 8)    // 2176 elems = 4352 B; 10 rows = 43520 B

union U4 { uint4 u; bf16 h[8]; short8 s8; };

__global__ __launch_bounds__(256) void k3_conv(
    const bf16* __restrict__ nx, const float2* __restrict__ sms,
    const float* __restrict__ gg, const float* __restrict__ bb,
    const bf16* __restrict__ wA, float* __restrict__ out)
{
    int w0 = blockIdx.x * PXB;   // 0..7 -> 0..224
    int h0 = blockIdx.y * ROWS;  // 0..31 -> 0..248
    int s  = blockIdx.z;
    int t  = threadIdx.x;
    __shared__ __align__(16) bf16 tile[TR * ROW_ELEMS];
    __shared__ float2 sbi[64];           // {b[o], 1/g[o]} for reconstruction
    if (t < 64) sbi[t] = make_float2(bb[t], 1.0f / gg[t]);

    // ---- P1: copy-stage tile from channel-last nx ----
    int p0 = t, p1 = t + 256;
    bool live1 = (p1 < NSITES);          // threads 0..83 own a second site
    int dr0 = p0 / WL, wl0 = p0 - dr0 * WL;
    int dr1 = live1 ? (p1 / WL) : 0;
    int wl1 = live1 ? (p1 - dr1 * WL) : 0;
    int grow0 = h0 + dr0 - 1, wab0 = w0 + wl0 - 1;
    int grow1 = h0 + dr1 - 1, wab1 = w0 + wl1 - 1;
    bool ok0 = (grow0 >= 0 && grow0 < Hd && wab0 >= 0 && wab0 < Wd);
    bool ok1 = live1 && (grow1 >= 0 && grow1 < Hd && wab1 >= 0 && wab1 < Wd);
    const bf16* np0 = nx + ((size_t)s * HW + (size_t)grow0 * Wd + wab0) * CO;
    const bf16* np1 = nx + ((size_t)s * HW + (size_t)grow1 * Wd + wab1) * CO;
    bf16* dst0 = &tile[dr0 * ROW_ELEMS + wl0 * 8];
    bf16* dst1 = &tile[dr1 * ROW_ELEMS + wl1 * 8];
    uint4 z = make_uint4(0u, 0u, 0u, 0u);
#pragma unroll
    for (int c8 = 0; c8 < 8; ++c8) {
        uint4 a = ok0 ? *(const uint4*)&np0[c8 * 8] : z;
        *(uint4*)&dst0[c8 * (WL * 8)] = a;
    }
    if (live1) {
#pragma unroll
        for (int c8 = 0; c8 < 8; ++c8) {
            uint4 a = ok1 ? *(const uint4*)&np1[c8 * 8] : z;
            *(uint4*)&dst1[c8 * (WL * 8)] = a;
        }
    }

    int wave = t >> 6, lane = t & 63;
    int mi = wave & 1, ni = wave >> 1;   // wave: o in [mi*32,+32), px in [ni*16,+16)
    int col = lane & 15, quad = lane >> 4;

    // ---- prefetch kc=0 A-pair + per-row sms (latency hides under LDS drain)
    const bf16* wAs = wA + s * (18 * 64 * 32);
    const bf16* pa0 = wAs + (mi * 32 + col) * 32 + quad * 8;
    const bf16* pa1 = wAs + (mi * 32 + 16 + col) * 32 + quad * 8;
    U4 a0c, a1c;
    a0c.u = *(const uint4*)pa0;
    a1c.u = *(const uint4*)pa1;

    int wpx = w0 + ni * 16 + col;
    float2 msr[ROWS];
#pragma unroll
    for (int r = 0; r < ROWS; ++r)
        msr[r] = sms[(size_t)s * HW + (size_t)(h0 + r) * Wd + wpx];

    __syncthreads();   // the ONLY barrier

    // hoist per-thread reconstruction constants (8 o's, fixed per thread)
    float2 bi8[2][4];
#pragma unroll
    for (int mt = 0; mt < 2; ++mt)
#pragma unroll
        for (int rr = 0; rr < 4; ++rr)
            bi8[mt][rr] = sbi[mi * 32 + mt * 16 + quad * 4 + rr];

    // ---- compute: kc-outer (unroll 1, A double-buffered), row-inner ----
    float4v acc[2][ROWS];
#pragma unroll
    for (int mt = 0; mt < 2; ++mt)
#pragma unroll
        for (int r = 0; r < ROWS; ++r) acc[mt][r] = (float4v)0.f;

    int base = ni * 16 + col;
#pragma unroll 1
    for (int kc = 0; kc < 18; ++kc) {
        // prefetch next kc (kc=18 read stays inside the 1 MB wA region: safe)
        U4 a0n, a1n;
        a0n.u = *(const uint4*)(pa0 + (kc + 1) * 2048);
        a1n.u = *(const uint4*)(pa1 + (kc + 1) * 2048);
        int tap = kc >> 1;
        int kh = (tap * 11) >> 5;            // tap/3 for tap in 0..8
        int kw = tap - kh * 3;
        int ch8 = (kc & 1) * 4 + quad;
        const bf16* bp = &tile[kh * ROW_ELEMS + (ch8 * WL + base + kw) * 8];
#pragma unroll
        for (int r = 0; r < ROWS; ++r) {
            U4 b; b.u = *(const uint4*)&bp[r * ROW_ELEMS];
            acc[0][r] = __builtin_amdgcn_mfma_f32_16x16x32_bf16(a0c.s8, b.s8, acc[0][r], 0, 0, 0);
            acc[1][r] = __builtin_amdgcn_mfma_f32_16x16x32_bf16(a1c.s8, b.s8, acc[1][r], 0, 0, 0);
        }
        a0c = a0n; a1c = a1n;
    }

    // ---- epilogue: residual from LDS tile (b64: 4 consecutive o) ----
    int wl_i = base + 1;
#pragma unroll
    for (int r = 0; r < ROWS; ++r) {
        int grow = h0 + r;
        float2 ms = msr[r];
#pragma unroll
        for (int mt = 0; mt < 2; ++mt) {
            int o0 = mi * 32 + mt * 16 + quad * 4;    // 4 consecutive o
            int c8o = o0 >> 3;
            union { uint2 u; bf16 hh[4]; } nv;
            nv.u = *(const uint2*)&tile[(r + 1) * ROW_ELEMS + (c8o * WL + wl_i) * 8 + (o0 & 7)];
            size_t idx0 = (size_t)(s * CO + o0) * HW + (size_t)grow * Wd + wpx;
#pragma unroll
            for (int rr = 0; rr < 4; ++rr) {
                float2 bi = bi8[mt][rr];
                float xrec = (__bfloat162float(nv.hh[rr]) - bi.x) * bi.y * ms.y + ms.x;
                out[idx0 + (size_t)rr * HW] = acc[mt][r][rr] + xrec;
            }
        }
    }
}

extern "C" void kernel_launch(void* const* d_in, const int* in_sizes, int n_in,
                              void* d_out, int out_size, void* d_ws, size_t ws_size,
                              hipStream_t stream)
{
    const float* x     = (const float*)d_in[0];
    const float* vec   = (const float*)d_in[1];
    const float* g     = (const float*)d_in[2];
    const float* bb    = (const float*)d_in[3];
    const float* w1    = (const float*)d_in[4];
    const float* w2    = (const float*)d_in[5];
    const float* wconv = (const float*)d_in[6];
    float* out = (float*)d_out;

    // workspace layout (ws_size >= 80 MB confirmed by R5 probe):
    //   [0, 1M)        wA   : 8*18*64*32 bf16 (576 KB + prefetch slack)
    //   [1M, 65M)      nx   : 8*65536*64 bf16 channel-last = 64 MB
    //   [65M, 69M)     sms  : 8*65536 float2 = 4 MB
    char* wsb = (char*)d_ws;
    bf16*   wA  = (bf16*)wsb;
    bf16*   nx  = (bf16*)(wsb + ((size_t)1 << 20));
    float2* sms = (float2*)(wsb + ((size_t)65 << 20));

    k1_style<<<dim3(64, 8), 64, 0, stream>>>(vec, w1, w2, wconv, wA);
    k2_norm<<<dim3(512, 8), 256, 0, stream>>>(x, g, bb, nx, sms);
    k3_conv<<<dim3(8, 32, 8), 256, 0, stream>>>(nx, sms, g, bb, wA, out);
}